// Round 9
// baseline (238.710 us; speedup 1.0000x reference)
//
#include <hip/hip_runtime.h>
#include <hip/hip_bf16.h>

// Problem dims (fixed by the reference)
constexpr int B_  = 4;
constexpr int S_  = 2048;
constexpr int D_  = 512;
constexpr int H_  = 8;
constexpr int HD_ = 64;
constexpr int M_  = B_ * S_;   // 8192

constexpr float LOG2E = 1.4426950408889634f;

typedef __attribute__((ext_vector_type(8))) short short8v;            // 8 bf16 (4 VGPR) MFMA operand
typedef __attribute__((ext_vector_type(8))) unsigned short ushort8v;  // 16B staging chunk
typedef __attribute__((ext_vector_type(4))) float float4v;            // MFMA C/D

__device__ __forceinline__ unsigned short f2bf(float x) {  // RNE fp32->bf16
    unsigned u = __builtin_bit_cast(unsigned, x);
    u += 0x7fffu + ((u >> 16) & 1u);
    return (unsigned short)(u >> 16);
}
__device__ __forceinline__ unsigned short f2bf_trunc(float x) {  // truncate (1 op)
    return (unsigned short)(__builtin_bit_cast(unsigned, x) >> 16);
}
__device__ __forceinline__ float bf2f(unsigned short h) {
    return __builtin_bit_cast(float, ((unsigned)h) << 16);
}
__device__ __forceinline__ float fast_exp2(float x) {
#if __has_builtin(__builtin_amdgcn_exp2f)
    return __builtin_amdgcn_exp2f(x);
#else
    return exp2f(x);
#endif
}
// async global->LDS, 16B per lane; lds dest = wave-uniform base + lane*16
__device__ __forceinline__ void gload_lds16(const void* g, void* lds) {
    __builtin_amdgcn_global_load_lds((const __attribute__((address_space(1))) unsigned*)g,
                                     (__attribute__((address_space(3))) unsigned*)lds, 16, 0, 0);
}

// ---------------------------------------------------------------------------
// Prepass: build bf16 operands (unchanged from R8).
// ---------------------------------------------------------------------------
__global__ __launch_bounds__(256) void prepass(const float* __restrict__ x,
                                               const float* __restrict__ wqkv,
                                               const float* __restrict__ wout,
                                               unsigned short* __restrict__ Xp,
                                               unsigned short* __restrict__ Wh,
                                               unsigned short* __restrict__ Wlq,
                                               unsigned short* __restrict__ Wob) {
    const int bid = blockIdx.x, t = threadIdx.x;
    if (bid < 2048) {                      // x
        const int flat = bid * 256 + t;
        const int m = flat >> 6, c = (flat & 63) * 8;
        const float4 a = *(const float4*)&x[(size_t)m * 512 + c];
        const float4 b = *(const float4*)&x[(size_t)m * 512 + c + 4];
        const float v[8] = {a.x, a.y, a.z, a.w, b.x, b.y, b.z, b.w};
        ushort8v hi, lo;
#pragma unroll
        for (int i = 0; i < 8; ++i) {
            const unsigned short h = f2bf(v[i]);
            hi[i] = h; lo[i] = f2bf(v[i] - bf2f(h));
        }
        *(ushort8v*)&Xp[(size_t)m * 1024 + c]       = hi;
        *(ushort8v*)&Xp[(size_t)m * 1024 + 512 + c] = lo;
    } else if (bid < 2048 + 384) {         // w_qkv
        const int flat = (bid - 2048) * 256 + t;
        const int e = flat >> 6, c = (flat & 63) * 8;
        const float4 a = *(const float4*)&wqkv[(size_t)e * 512 + c];
        const float4 b = *(const float4*)&wqkv[(size_t)e * 512 + c + 4];
        const float v[8] = {a.x, a.y, a.z, a.w, b.x, b.y, b.z, b.w};
        ushort8v hi, lo;
#pragma unroll
        for (int i = 0; i < 8; ++i) {
            const unsigned short h = f2bf(v[i]);
            hi[i] = h; lo[i] = f2bf(v[i] - bf2f(h));
        }
        *(ushort8v*)&Wh[(size_t)e * 512 + c] = hi;
        if (e < 512) *(ushort8v*)&Wlq[(size_t)e * 512 + c] = lo;
    } else {                               // w_out
        const int flat = (bid - 2432) * 256 + t;
        const int e = flat >> 6, c = (flat & 63) * 8;
        const float4 a = *(const float4*)&wout[(size_t)e * 512 + c];
        const float4 b = *(const float4*)&wout[(size_t)e * 512 + c + 4];
        const float v[8] = {a.x, a.y, a.z, a.w, b.x, b.y, b.z, b.w};
        ushort8v hi;
#pragma unroll
        for (int i = 0; i < 8; ++i) hi[i] = f2bf(v[i]);
        *(ushort8v*)&Wob[(size_t)e * 512 + c] = hi;
    }
}

// ---------------------------------------------------------------------------
// GEMM1 (QKV projection) — unchanged from R8 (dbuf + prefetch).
// ---------------------------------------------------------------------------
__global__ __launch_bounds__(256) void gemm_qkv(const unsigned short* __restrict__ Xp,
                                                const unsigned short* __restrict__ Wh,
                                                const unsigned short* __restrict__ Wlq,
                                                unsigned short* __restrict__ QmH,
                                                unsigned short* __restrict__ QmL,
                                                unsigned short* __restrict__ Cc,
                                                unsigned short* __restrict__ KH,
                                                unsigned short* __restrict__ VT) {
    __shared__ unsigned short Asm[2][128 * 64];
    __shared__ unsigned short Bsm[2][128 * 64];
    const int t = threadIdx.x, wv = t >> 6, lane = t & 63;
    const int fm = lane & 15, fq = lane >> 4;
    const int m0 = blockIdx.y * 128;
    const int x  = blockIdx.x;
    const int slice = x >> 2;            // 0=qcorr 1=qmain 2=k 3=v
    const int e0 = (x & 3) * 128;
    const bool vblk = (slice == 3);
    const int kiters = (slice == 0) ? 16 : 8;
    const int wrow = (wv >> 1) * 64, wcol = (wv & 1) * 64;

    const unsigned short* BbaseWh =
        Wh + (size_t)(e0 + (slice == 2 ? 512 : (slice == 3 ? 1024 : 0))) * 512;
    const unsigned short* BbaseWlq = Wlq + (size_t)e0 * 512;

    const int srow = t >> 3;
    const int skb0 = t & 7;

    float4v acc[4][4];
#pragma unroll
    for (int i = 0; i < 4; ++i)
#pragma unroll
        for (int j = 0; j < 4; ++j) acc[i][j] = (float4v){0.f, 0.f, 0.f, 0.f};

    {
        const int aoff = (slice == 0) ? 512 : 0;
#pragma unroll
        for (int i = 0; i < 4; ++i) {
            const int row = srow + 32 * i;
            const int kb = (skb0 ^ (row & 7));
            gload_lds16(Xp + (size_t)(m0 + row) * 1024 + aoff + kb * 8,
                        &Asm[0][(wv * 64 + 256 * i) * 8]);
            gload_lds16(BbaseWh + (size_t)row * 512 + kb * 8,
                        &Bsm[0][(wv * 64 + 256 * i) * 8]);
        }
    }

    for (int kk = 0; kk < kiters; ++kk) {
        __syncthreads();

        if (kk + 1 < kiters) {
            const int nk = kk + 1;
            const int pass = nk >> 3;
            const int k0n = (nk & 7) * 64;
            const int nbuf = nk & 1;
            const int aoff = (slice == 0 && pass == 0) ? 512 : 0;
            const unsigned short* Bp = (slice == 0 && pass == 1) ? BbaseWlq : BbaseWh;
#pragma unroll
            for (int i = 0; i < 4; ++i) {
                const int row = srow + 32 * i;
                const int kb = (skb0 ^ (row & 7));
                gload_lds16(Xp + (size_t)(m0 + row) * 1024 + aoff + k0n + kb * 8,
                            &Asm[nbuf][(wv * 64 + 256 * i) * 8]);
                gload_lds16(Bp + (size_t)row * 512 + k0n + kb * 8,
                            &Bsm[nbuf][(wv * 64 + 256 * i) * 8]);
            }
        }

        const int buf = kk & 1;
#pragma unroll
        for (int ks = 0; ks < 2; ++ks) {
            short8v af[4], bf[4];
#pragma unroll
            for (int mt = 0; mt < 4; ++mt) {
                const int row = wrow + mt * 16 + fm;
                af[mt] = *(const short8v*)&Asm[buf][row * 64 + 8 * ((4 * ks + fq) ^ (row & 7))];
            }
#pragma unroll
            for (int nt = 0; nt < 4; ++nt) {
                const int row = wcol + nt * 16 + fm;
                bf[nt] = *(const short8v*)&Bsm[buf][row * 64 + 8 * ((4 * ks + fq) ^ (row & 7))];
            }
            if (vblk) {
#pragma unroll
                for (int mt = 0; mt < 4; ++mt)
#pragma unroll
                    for (int nt = 0; nt < 4; ++nt)
                        acc[mt][nt] = __builtin_amdgcn_mfma_f32_16x16x32_bf16(bf[nt], af[mt], acc[mt][nt], 0, 0, 0);
            } else {
#pragma unroll
                for (int mt = 0; mt < 4; ++mt)
#pragma unroll
                    for (int nt = 0; nt < 4; ++nt)
                        acc[mt][nt] = __builtin_amdgcn_mfma_f32_16x16x32_bf16(af[mt], bf[nt], acc[mt][nt], 0, 0, 0);
            }
        }
    }

    if (slice == 1) {
#pragma unroll
        for (int mt = 0; mt < 4; ++mt)
#pragma unroll
            for (int nt = 0; nt < 4; ++nt) {
                const int e = e0 + wcol + nt * 16 + fm;
                const int h = e >> 6, hd = e & 63;
#pragma unroll
                for (int r = 0; r < 4; ++r) {
                    const int m = m0 + wrow + mt * 16 + 4 * fq + r;
                    const int b = m >> 11, s = m & 2047;
                    const float v = acc[mt][nt][r];
                    const unsigned short hh = f2bf(v);
                    const size_t idx = ((size_t)(b * 8 + h) * 2048 + s) * 64 + hd;
                    QmH[idx] = hh;
                    QmL[idx] = f2bf(v - bf2f(hh));
                }
            }
    } else if (slice == 0 || slice == 2) {
        unsigned short* __restrict__ dst = (slice == 0) ? Cc : KH;
#pragma unroll
        for (int mt = 0; mt < 4; ++mt)
#pragma unroll
            for (int nt = 0; nt < 4; ++nt) {
                const int e = e0 + wcol + nt * 16 + fm;
                const int h = e >> 6, hd = e & 63;
#pragma unroll
                for (int r = 0; r < 4; ++r) {
                    const int m = m0 + wrow + mt * 16 + 4 * fq + r;
                    const int b = m >> 11, s = m & 2047;
                    dst[((size_t)(b * 8 + h) * 2048 + s) * 64 + hd] = f2bf(acc[mt][nt][r]);
                }
            }
    } else {
#pragma unroll
        for (int nt = 0; nt < 4; ++nt)
#pragma unroll
            for (int r = 0; r < 4; ++r) {
                const int e = e0 + wcol + nt * 16 + 4 * fq + r;
                const int h = e >> 6, hd = e & 63;
#pragma unroll
                for (int mt = 0; mt < 4; ++mt) {
                    const int m = m0 + wrow + mt * 16 + fm;
                    const int b = m >> 11, s = m & 2047;
                    VT[((size_t)(b * 8 + h) * 64 + hd) * 2048 + s] = f2bf(acc[mt][nt][r]);
                }
            }
    }
}

// ---------------------------------------------------------------------------
// MFMA flash attention, SPLIT-J (exact: no online max needed).
// Block = (q-tile of 128, bh, split); split covers j in [split*1024, +1024).
// Emits UNNORMALIZED partials: OP[split][b][s][d] bf16, LP[split][bh][s] fp32.
// Grid 1024 blocks (2x R8) -> breaks the 2-blocks/CU grid cap.
// ---------------------------------------------------------------------------
__global__ __launch_bounds__(256) void attn(const unsigned short* __restrict__ QmHp,
                                            const unsigned short* __restrict__ QmLp,
                                            const unsigned short* __restrict__ Ccp,
                                            const unsigned short* __restrict__ KHp,
                                            const unsigned short* __restrict__ VTp,
                                            unsigned short* __restrict__ OP,
                                            float* __restrict__ LP) {
    __shared__ unsigned short KsH[2][64 * 64], Vs[2][64 * 64];
    __shared__ unsigned short Ph[4][32 * 72];
    const int t = threadIdx.x, wv = t >> 6, lane = t & 63;
    const int fm = lane & 15, fq = lane >> 4;
    const int bh = blockIdx.y, q0 = blockIdx.x * 128;
    const int split = blockIdx.z;
    const int jbase = split * 1024;

    const unsigned short* qmh = QmHp + (size_t)bh * S_ * 64;
    const unsigned short* qml = QmLp + (size_t)bh * S_ * 64;
    const unsigned short* qcc = Ccp  + (size_t)bh * S_ * 64;
    const unsigned short* kh  = KHp  + (size_t)bh * S_ * 64;
    const unsigned short* vt  = VTp  + (size_t)bh * 64 * S_;

    const int srow = t >> 3;
    const int skb0 = t & 7;

    // prologue: stage K/V tile jt=0 of this split into buf 0
#pragma unroll
    for (int i = 0; i < 2; ++i) {
        const int row = srow + 32 * i;
        const int kb = skb0 ^ (row & 7);
        const int dst = (wv * 64 + 256 * i) * 8;
        gload_lds16(kh + (size_t)(jbase + row) * 64 + kb * 8, &KsH[0][dst]);
        gload_lds16(vt + (size_t)row * S_ + jbase + kb * 8, &Vs[0][dst]);
    }

    // Assemble Q fragments: q = (Qm + C) * log2e, split hi/lo
    short8v qfh[2][2], qfl[2][2];
#pragma unroll
    for (int qt = 0; qt < 2; ++qt)
#pragma unroll
        for (int t2 = 0; t2 < 2; ++t2) {
            const size_t off = (size_t)(q0 + wv * 32 + qt * 16 + fm) * 64 + t2 * 32 + fq * 8;
            const ushort8v mh = *(const ushort8v*)&qmh[off];
            const ushort8v ml = *(const ushort8v*)&qml[off];
            const ushort8v cc = *(const ushort8v*)&qcc[off];
#pragma unroll
            for (int i = 0; i < 8; ++i) {
                const float v = (bf2f(mh[i]) + bf2f(ml[i]) + bf2f(cc[i])) * LOG2E;
                const unsigned short hh = f2bf(v);
                qfh[qt][t2][i] = (short)hh;
                qfl[qt][t2][i] = (short)f2bf(v - bf2f(hh));
            }
        }

    float4v accO[2][4];
#pragma unroll
    for (int qt = 0; qt < 2; ++qt)
#pragma unroll
        for (int dt = 0; dt < 4; ++dt) accO[qt][dt] = (float4v){0.f, 0.f, 0.f, 0.f};
    float lpart[2][4] = {};

    for (int jt = 0; jt < 16; ++jt) {
        __syncthreads();

        if (jt + 1 < 16) {
            const int j0n = jbase + (jt + 1) * 64;
            const int nbuf = (jt + 1) & 1;
#pragma unroll
            for (int i = 0; i < 2; ++i) {
                const int row = srow + 32 * i;
                const int kb = skb0 ^ (row & 7);
                const int dst = (wv * 64 + 256 * i) * 8;
                gload_lds16(kh + (size_t)(j0n + row) * 64 + kb * 8, &KsH[nbuf][dst]);
                gload_lds16(vt + (size_t)row * S_ + j0n + kb * 8, &Vs[nbuf][dst]);
            }
        }
        const int buf = jt & 1;

        // S = Q K^T (qh.k + ql.k)
        float4v accS[2][4];
#pragma unroll
        for (int qt = 0; qt < 2; ++qt)
#pragma unroll
            for (int st = 0; st < 4; ++st) accS[qt][st] = (float4v){0.f, 0.f, 0.f, 0.f};
#pragma unroll
        for (int t2 = 0; t2 < 2; ++t2)
#pragma unroll
            for (int st = 0; st < 4; ++st) {
                const int row = st * 16 + fm;
                const short8v kf = *(const short8v*)&KsH[buf][row * 64 + 8 * ((4 * t2 + fq) ^ (row & 7))];
#pragma unroll
                for (int qt = 0; qt < 2; ++qt) {
                    accS[qt][st] = __builtin_amdgcn_mfma_f32_16x16x32_bf16(qfh[qt][t2], kf, accS[qt][st], 0, 0, 0);
                    accS[qt][st] = __builtin_amdgcn_mfma_f32_16x16x32_bf16(qfl[qt][t2], kf, accS[qt][st], 0, 0, 0);
                }
            }

        // P = exp2(S); accumulate l; store P (trunc bf16) with rotation swizzle
#pragma unroll
        for (int qt = 0; qt < 2; ++qt)
#pragma unroll
            for (int st = 0; st < 4; ++st)
#pragma unroll
                for (int r = 0; r < 4; ++r) {
                    const float p = fast_exp2(accS[qt][st][r]);
                    lpart[qt][r] += p;
                    const int row = qt * 16 + 4 * fq + r;
                    Ph[wv][row * 72 + ((st * 16 + fm + 16 * fq) & 63)] = f2bf_trunc(p);
                }

        // O += P V (wave-private P buffer)
#pragma unroll
        for (int t2 = 0; t2 < 2; ++t2) {
            short8v pa[2];
#pragma unroll
            for (int qt = 0; qt < 2; ++qt) {
                const int row = qt * 16 + fm;
                pa[qt] = *(const short8v*)&Ph[wv][row * 72 + ((t2 * 32 + fq * 8 + 16 * (fm >> 2)) & 63)];
            }
#pragma unroll
            for (int dt = 0; dt < 4; ++dt) {
                const int vrow = dt * 16 + fm;
                const short8v vf = *(const short8v*)&Vs[buf][vrow * 64 + 8 * ((4 * t2 + fq) ^ (vrow & 7))];
#pragma unroll
                for (int qt = 0; qt < 2; ++qt)
                    accO[qt][dt] = __builtin_amdgcn_mfma_f32_16x16x32_bf16(pa[qt], vf, accO[qt][dt], 0, 0, 0);
            }
        }
    }

    // reduce l across the 16 m-lanes; lane fm==0 stores per-row l
#pragma unroll
    for (int qt = 0; qt < 2; ++qt)
#pragma unroll
        for (int r = 0; r < 4; ++r) {
            float v = lpart[qt][r];
            v += __shfl_xor(v, 1); v += __shfl_xor(v, 2);
            v += __shfl_xor(v, 4); v += __shfl_xor(v, 8);
            lpart[qt][r] = v;
        }
    if (fm == 0) {
#pragma unroll
        for (int qt = 0; qt < 2; ++qt)
#pragma unroll
            for (int r = 0; r < 4; ++r) {
                const int q = q0 + wv * 32 + qt * 16 + 4 * fq + r;
                LP[((size_t)split * 32 + bh) * S_ + q] = lpart[qt][r];
            }
    }

    // epilogue: UNNORMALIZED partial O as bf16 into OP[split][b][s][h*64+d]
    const int b = bh >> 3, h = bh & 7;
    unsigned short* __restrict__ OPs = OP + (size_t)split * M_ * D_;
#pragma unroll
    for (int qt = 0; qt < 2; ++qt)
#pragma unroll
        for (int r = 0; r < 4; ++r) {
            const int q = q0 + wv * 32 + qt * 16 + 4 * fq + r;
#pragma unroll
            for (int dt = 0; dt < 4; ++dt)
                OPs[((size_t)(b * 2048 + q)) * 512 + h * 64 + dt * 16 + fm] =
                    f2bf(accO[qt][dt][r]);
        }
}

// ---------------------------------------------------------------------------
// GEMM2 (out projection) with FUSED split-combine in A-staging:
//   a[m][d] = (O1[m][d] + O2[m][d]) / (l1[bh(d),s(m)] + l2[...])
// A staged via plain loads + VALU combine + ds_write (same swizzled layout
// the DMA produced); B (weights) still DMA. Single-buffer, 2 barriers/iter.
// ---------------------------------------------------------------------------
__global__ __launch_bounds__(256) void gemm_out(const unsigned short* __restrict__ OP,
                                                const float* __restrict__ LP,
                                                const unsigned short* __restrict__ Wob,
                                                float* __restrict__ out) {
    __shared__ unsigned short Asm[128 * 64];
    __shared__ unsigned short Bsm[64 * 64];
    const int t = threadIdx.x, wv = t >> 6, lane = t & 63;
    const int fm = lane & 15, fq = lane >> 4;
    const int m0 = blockIdx.y * 128, e0 = blockIdx.x * 64;
    const int wrow = (wv & 1) * 64, wcol = (wv >> 1) * 32;

    const int srow = t >> 3;
    const int skb0 = t & 7;
    const unsigned short* O2 = OP + (size_t)M_ * D_;

    float4v acc[4][2];
#pragma unroll
    for (int i = 0; i < 4; ++i)
#pragma unroll
        for (int j = 0; j < 2; ++j) acc[i][j] = (float4v){0.f, 0.f, 0.f, 0.f};

    for (int kk = 0; kk < 8; ++kk) {
        const int k0 = kk * 64;
        // A-tile loads (global->VGPR) for tile kk, issued before the barrier
        ushort8v o1v[4], o2v[4];
        float invv[4];
#pragma unroll
        for (int i = 0; i < 4; ++i) {
            const int row = srow + 32 * i;           // m-offset in tile
            const int kb = skb0 ^ (row & 7);
            const int c = k0 + kb * 8;               // column (d), within head c>>6
            const int m = m0 + row;
            const int b = m >> 11, s = m & 2047;
            const int bh = b * 8 + (c >> 6);
            const size_t go = (size_t)m * 512 + c;
            o1v[i] = *(const ushort8v*)&OP[go];
            o2v[i] = *(const ushort8v*)&O2[go];
            invv[i] = 1.f / (LP[(size_t)bh * S_ + s] + LP[((size_t)32 + bh) * S_ + s]);
        }
        __syncthreads();   // waves done computing tile kk-1 from LDS
        // B via DMA; A via combine + ds_write (same layout as DMA: slot*16B)
#pragma unroll
        for (int i = 0; i < 2; ++i) {
            const int row = srow + 32 * i;
            const int kb = skb0 ^ (row & 7);
            gload_lds16(Wob + (size_t)(e0 + row) * 512 + k0 + kb * 8,
                        &Bsm[(wv * 64 + 256 * i) * 8]);
        }
#pragma unroll
        for (int i = 0; i < 4; ++i) {
            ushort8v av;
#pragma unroll
            for (int j = 0; j < 8; ++j)
                av[j] = f2bf((bf2f(o1v[i][j]) + bf2f(o2v[i][j])) * invv[i]);
            *(ushort8v*)&Asm[(t + 256 * i) * 8] = av;
        }
        __syncthreads();   // ds_writes visible + DMA drained

#pragma unroll
        for (int ks = 0; ks < 2; ++ks) {
            short8v af[4], bf[2];
#pragma unroll
            for (int mt = 0; mt < 4; ++mt) {
                const int row = wrow + mt * 16 + fm;
                af[mt] = *(const short8v*)&Asm[row * 64 + 8 * ((4 * ks + fq) ^ (row & 7))];
            }
#pragma unroll
            for (int nt = 0; nt < 2; ++nt) {
                const int row = wcol + nt * 16 + fm;
                bf[nt] = *(const short8v*)&Bsm[row * 64 + 8 * ((4 * ks + fq) ^ (row & 7))];
            }
#pragma unroll
            for (int mt = 0; mt < 4; ++mt)
#pragma unroll
                for (int nt = 0; nt < 2; ++nt)
                    acc[mt][nt] = __builtin_amdgcn_mfma_f32_16x16x32_bf16(af[mt], bf[nt], acc[mt][nt], 0, 0, 0);
        }
    }
#pragma unroll
    for (int mt = 0; mt < 4; ++mt)
#pragma unroll
        for (int nt = 0; nt < 2; ++nt)
#pragma unroll
            for (int r = 0; r < 4; ++r) {
                const int m = m0 + wrow + mt * 16 + 4 * fq + r;
                const int e = e0 + wcol + nt * 16 + fm;
                out[(size_t)m * 512 + e] = acc[mt][nt][r];
            }
}

// ---------------------------------------------------------------------------
extern "C" void kernel_launch(void* const* d_in, const int* in_sizes, int n_in,
                              void* d_out, int out_size, void* d_ws, size_t ws_size,
                              hipStream_t stream) {
    const float* x     = (const float*)d_in[0];   // [B,S,D]
    const float* w_qkv = (const float*)d_in[1];   // [3D, D]
    const float* w_out = (const float*)d_in[2];   // [D, D]
    float* out = (float*)d_out;                   // [B,S,D]

    // workspace carve-up (bytes): total ~61.9 MB
    char* p = (char*)d_ws;
    unsigned short* Xp  = (unsigned short*)p;  p += (size_t)M_ * 1024 * 2;      // 16.8 MB
    unsigned short* Wh  = (unsigned short*)p;  p += (size_t)1536 * 512 * 2;     // 1.6 MB
    unsigned short* Wlq = (unsigned short*)p;  p += (size_t)512 * 512 * 2;      // 0.5 MB
    unsigned short* Wob = (unsigned short*)p;  p += (size_t)512 * 512 * 2;      // 0.5 MB
    unsigned short* QmH = (unsigned short*)p;  p += (size_t)32 * S_ * 64 * 2;   // 8.4 MB
    unsigned short* QmL = (unsigned short*)p;  p += (size_t)32 * S_ * 64 * 2;
    unsigned short* Cc  = (unsigned short*)p;  p += (size_t)32 * S_ * 64 * 2;
    unsigned short* KH  = (unsigned short*)p;  p += (size_t)32 * S_ * 64 * 2;
    unsigned short* VT  = (unsigned short*)p;  p += (size_t)32 * 64 * S_ * 2;   // 8.4 MB
    float*          LPb = (float*)p;           p += (size_t)2 * 32 * S_ * 4;    // 0.5 MB
    unsigned short* OP  = Xp;  // Xp dead after gemm_qkv; holds 2 bf16 O-partials (16.8 MB exact)

    prepass<<<2560, 256, 0, stream>>>(x, w_qkv, w_out, Xp, Wh, Wlq, Wob);
    gemm_qkv<<<dim3(16, 64), 256, 0, stream>>>(Xp, Wh, Wlq, QmH, QmL, Cc, KH, VT);
    attn<<<dim3(16, 32, 2), 256, 0, stream>>>(QmH, QmL, Cc, KH, VT, OP, LPb);
    gemm_out<<<dim3(8, 64), 256, 0, stream>>>(OP, LPb, Wob, out);
}

// Round 10
// 201.822 us; speedup vs baseline: 1.1828x; 1.1828x over previous
//
#include <hip/hip_runtime.h>
#include <hip/hip_bf16.h>

// Problem dims (fixed by the reference)
constexpr int B_  = 4;
constexpr int S_  = 2048;
constexpr int D_  = 512;
constexpr int H_  = 8;
constexpr int HD_ = 64;
constexpr int M_  = B_ * S_;   // 8192

constexpr float LOG2E = 1.4426950408889634f;

typedef __attribute__((ext_vector_type(8))) short short8v;            // 8 bf16 (4 VGPR) MFMA operand
typedef __attribute__((ext_vector_type(8))) unsigned short ushort8v;  // 16B staging chunk
typedef __attribute__((ext_vector_type(4))) float float4v;            // MFMA C/D

__device__ __forceinline__ unsigned short f2bf(float x) {  // RNE fp32->bf16
    unsigned u = __builtin_bit_cast(unsigned, x);
    u += 0x7fffu + ((u >> 16) & 1u);
    return (unsigned short)(u >> 16);
}
__device__ __forceinline__ unsigned short f2bf_trunc(float x) {  // truncate (1 op)
    return (unsigned short)(__builtin_bit_cast(unsigned, x) >> 16);
}
__device__ __forceinline__ float bf2f(unsigned short h) {
    return __builtin_bit_cast(float, ((unsigned)h) << 16);
}
__device__ __forceinline__ float fast_exp2(float x) {
#if __has_builtin(__builtin_amdgcn_exp2f)
    return __builtin_amdgcn_exp2f(x);
#else
    return exp2f(x);
#endif
}
// async global->LDS, 16B per lane; lds dest = wave-uniform base + lane*16
__device__ __forceinline__ void gload_lds16(const void* g, void* lds) {
    __builtin_amdgcn_global_load_lds((const __attribute__((address_space(1))) unsigned*)g,
                                     (__attribute__((address_space(3))) unsigned*)lds, 16, 0, 0);
}

// ---------------------------------------------------------------------------
// Prepass: build bf16 operands (R8 version).
//   Xp  [8192][1024]: cols [0:512)=hi(x), [512:1024)=lo(x)
//   Wh  [1536][512] : hi(w_qkv);  Wlq [512][512]: lo(w_q);  Wob: hi(w_out)
// ---------------------------------------------------------------------------
__global__ __launch_bounds__(256) void prepass(const float* __restrict__ x,
                                               const float* __restrict__ wqkv,
                                               const float* __restrict__ wout,
                                               unsigned short* __restrict__ Xp,
                                               unsigned short* __restrict__ Wh,
                                               unsigned short* __restrict__ Wlq,
                                               unsigned short* __restrict__ Wob) {
    const int bid = blockIdx.x, t = threadIdx.x;
    if (bid < 2048) {                      // x
        const int flat = bid * 256 + t;
        const int m = flat >> 6, c = (flat & 63) * 8;
        const float4 a = *(const float4*)&x[(size_t)m * 512 + c];
        const float4 b = *(const float4*)&x[(size_t)m * 512 + c + 4];
        const float v[8] = {a.x, a.y, a.z, a.w, b.x, b.y, b.z, b.w};
        ushort8v hi, lo;
#pragma unroll
        for (int i = 0; i < 8; ++i) {
            const unsigned short h = f2bf(v[i]);
            hi[i] = h; lo[i] = f2bf(v[i] - bf2f(h));
        }
        *(ushort8v*)&Xp[(size_t)m * 1024 + c]       = hi;
        *(ushort8v*)&Xp[(size_t)m * 1024 + 512 + c] = lo;
    } else if (bid < 2048 + 384) {         // w_qkv
        const int flat = (bid - 2048) * 256 + t;
        const int e = flat >> 6, c = (flat & 63) * 8;
        const float4 a = *(const float4*)&wqkv[(size_t)e * 512 + c];
        const float4 b = *(const float4*)&wqkv[(size_t)e * 512 + c + 4];
        const float v[8] = {a.x, a.y, a.z, a.w, b.x, b.y, b.z, b.w};
        ushort8v hi, lo;
#pragma unroll
        for (int i = 0; i < 8; ++i) {
            const unsigned short h = f2bf(v[i]);
            hi[i] = h; lo[i] = f2bf(v[i] - bf2f(h));
        }
        *(ushort8v*)&Wh[(size_t)e * 512 + c] = hi;
        if (e < 512) *(ushort8v*)&Wlq[(size_t)e * 512 + c] = lo;
    } else {                               // w_out
        const int flat = (bid - 2432) * 256 + t;
        const int e = flat >> 6, c = (flat & 63) * 8;
        const float4 a = *(const float4*)&wout[(size_t)e * 512 + c];
        const float4 b = *(const float4*)&wout[(size_t)e * 512 + c + 4];
        const float v[8] = {a.x, a.y, a.z, a.w, b.x, b.y, b.z, b.w};
        ushort8v hi;
#pragma unroll
        for (int i = 0; i < 8; ++i) hi[i] = f2bf(v[i]);
        *(ushort8v*)&Wob[(size_t)e * 512 + c] = hi;
    }
}

// ---------------------------------------------------------------------------
// GEMM1 (QKV projection): 128x64 tiles, BK=64, dbuf+prefetch, 1 barrier/iter.
// LDS 48 KB -> 3 blocks/CU; grid (32,64)=2048 blocks (8 blocks/CU of work).
// Slices: x>>3 = 0:qcorr(K=1024, dispatched first) 1:qmain 2:k 3:v (K=512).
// e0 = (x&7)*64 within the 512-wide segment.
// Wave layout: wrow=(wv>>1)*64, wcol=(wv&1)*32; acc[4][2].
// vblk: acc[mt][nt] = mfma(A=bf[nt], B=af[mt]) => D rows = e, cols = m.
// ---------------------------------------------------------------------------
__global__ __launch_bounds__(256, 3) void gemm_qkv(const unsigned short* __restrict__ Xp,
                                                   const unsigned short* __restrict__ Wh,
                                                   const unsigned short* __restrict__ Wlq,
                                                   unsigned short* __restrict__ QmH,
                                                   unsigned short* __restrict__ QmL,
                                                   unsigned short* __restrict__ Cc,
                                                   unsigned short* __restrict__ KH,
                                                   unsigned short* __restrict__ VT) {
    __shared__ unsigned short Asm[2][128 * 64];   // 32 KB
    __shared__ unsigned short Bsm[2][64 * 64];    // 16 KB
    const int t = threadIdx.x, wv = t >> 6, lane = t & 63;
    const int fm = lane & 15, fq = lane >> 4;
    const int m0 = blockIdx.y * 128;
    const int x  = blockIdx.x;
    const int slice = x >> 3;            // 0=qcorr 1=qmain 2=k 3=v
    const int e0 = (x & 7) * 64;         // within the 512-wide segment
    const bool vblk = (slice == 3);
    const int kiters = (slice == 0) ? 16 : 8;
    const int wrow = (wv >> 1) * 64, wcol = (wv & 1) * 32;

    const unsigned short* BbaseWh =
        Wh + (size_t)(e0 + (slice == 2 ? 512 : (slice == 3 ? 1024 : 0))) * 512;
    const unsigned short* BbaseWlq = Wlq + (size_t)e0 * 512;

    const int srow = t >> 3;     // 0..31; +32*i extends
    const int skb0 = t & 7;

    float4v acc[4][2];
#pragma unroll
    for (int i = 0; i < 4; ++i)
#pragma unroll
        for (int j = 0; j < 2; ++j) acc[i][j] = (float4v){0.f, 0.f, 0.f, 0.f};

    // prologue: stage tile kk=0 into buf 0
    {
        const int aoff = (slice == 0) ? 512 : 0;   // qcorr pass0 uses XL
#pragma unroll
        for (int i = 0; i < 4; ++i) {
            const int row = srow + 32 * i;
            const int kb = skb0 ^ (row & 7);
            gload_lds16(Xp + (size_t)(m0 + row) * 1024 + aoff + kb * 8,
                        &Asm[0][(wv * 64 + 256 * i) * 8]);
        }
#pragma unroll
        for (int i = 0; i < 2; ++i) {
            const int row = srow + 32 * i;
            const int kb = skb0 ^ (row & 7);
            gload_lds16(BbaseWh + (size_t)row * 512 + kb * 8,
                        &Bsm[0][(wv * 64 + 256 * i) * 8]);
        }
    }

    for (int kk = 0; kk < kiters; ++kk) {
        __syncthreads();   // tile kk DMA complete; buf[(kk+1)&1] free

        if (kk + 1 < kiters) {     // prefetch tile kk+1 (overlaps compute of kk)
            const int nk = kk + 1;
            const int pass = nk >> 3;
            const int k0n = (nk & 7) * 64;
            const int nbuf = nk & 1;
            const int aoff = (slice == 0 && pass == 0) ? 512 : 0;
            const unsigned short* Bp = (slice == 0 && pass == 1) ? BbaseWlq : BbaseWh;
#pragma unroll
            for (int i = 0; i < 4; ++i) {
                const int row = srow + 32 * i;
                const int kb = skb0 ^ (row & 7);
                gload_lds16(Xp + (size_t)(m0 + row) * 1024 + aoff + k0n + kb * 8,
                            &Asm[nbuf][(wv * 64 + 256 * i) * 8]);
            }
#pragma unroll
            for (int i = 0; i < 2; ++i) {
                const int row = srow + 32 * i;
                const int kb = skb0 ^ (row & 7);
                gload_lds16(Bp + (size_t)row * 512 + k0n + kb * 8,
                            &Bsm[nbuf][(wv * 64 + 256 * i) * 8]);
            }
        }

        const int buf = kk & 1;
#pragma unroll
        for (int ks = 0; ks < 2; ++ks) {
            short8v af[4], bf[2];
#pragma unroll
            for (int mt = 0; mt < 4; ++mt) {
                const int row = wrow + mt * 16 + fm;
                af[mt] = *(const short8v*)&Asm[buf][row * 64 + 8 * ((4 * ks + fq) ^ (row & 7))];
            }
#pragma unroll
            for (int nt = 0; nt < 2; ++nt) {
                const int row = wcol + nt * 16 + fm;
                bf[nt] = *(const short8v*)&Bsm[buf][row * 64 + 8 * ((4 * ks + fq) ^ (row & 7))];
            }
            if (vblk) {
#pragma unroll
                for (int mt = 0; mt < 4; ++mt)
#pragma unroll
                    for (int nt = 0; nt < 2; ++nt)
                        acc[mt][nt] = __builtin_amdgcn_mfma_f32_16x16x32_bf16(bf[nt], af[mt], acc[mt][nt], 0, 0, 0);
            } else {
#pragma unroll
                for (int mt = 0; mt < 4; ++mt)
#pragma unroll
                    for (int nt = 0; nt < 2; ++nt)
                        acc[mt][nt] = __builtin_amdgcn_mfma_f32_16x16x32_bf16(af[mt], bf[nt], acc[mt][nt], 0, 0, 0);
            }
        }
    }

    if (slice == 1) {
        // qmain: hi/lo split store (acc rows = m-block mt, cols = e-block nt)
#pragma unroll
        for (int mt = 0; mt < 4; ++mt)
#pragma unroll
            for (int nt = 0; nt < 2; ++nt) {
                const int e = e0 + wcol + nt * 16 + fm;
                const int h = e >> 6, hd = e & 63;
#pragma unroll
                for (int r = 0; r < 4; ++r) {
                    const int m = m0 + wrow + mt * 16 + 4 * fq + r;
                    const int b = m >> 11, s = m & 2047;
                    const float v = acc[mt][nt][r];
                    const unsigned short hh = f2bf(v);
                    const size_t idx = ((size_t)(b * 8 + h) * 2048 + s) * 64 + hd;
                    QmH[idx] = hh;
                    QmL[idx] = f2bf(v - bf2f(hh));
                }
            }
    } else if (slice == 0 || slice == 2) {
        // qcorr / k: single bf16 store
        unsigned short* __restrict__ dst = (slice == 0) ? Cc : KH;
#pragma unroll
        for (int mt = 0; mt < 4; ++mt)
#pragma unroll
            for (int nt = 0; nt < 2; ++nt) {
                const int e = e0 + wcol + nt * 16 + fm;
                const int h = e >> 6, hd = e & 63;
#pragma unroll
                for (int r = 0; r < 4; ++r) {
                    const int m = m0 + wrow + mt * 16 + 4 * fq + r;
                    const int b = m >> 11, s = m & 2047;
                    dst[((size_t)(b * 8 + h) * 2048 + s) * 64 + hd] = f2bf(acc[mt][nt][r]);
                }
            }
    } else {
        // v: acc[mt][nt] rows = e-block nt (4fq+r), cols = m-block mt (fm)
#pragma unroll
        for (int nt = 0; nt < 2; ++nt)
#pragma unroll
            for (int r = 0; r < 4; ++r) {
                const int e = e0 + wcol + nt * 16 + 4 * fq + r;
                const int h = e >> 6, hd = e & 63;
#pragma unroll
                for (int mt = 0; mt < 4; ++mt) {
                    const int m = m0 + wrow + mt * 16 + fm;
                    const int b = m >> 11, s = m & 2047;
                    VT[((size_t)(b * 8 + h) * 64 + hd) * 2048 + s] = f2bf(acc[mt][nt][r]);
                }
            }
    }
}

// ---------------------------------------------------------------------------
// MFMA flash attention (R8 version). Block = (bh, 128 q-rows); TJ=64.
// One barrier per j-iter + cross-iter K/V DMA prefetch (double-buffered).
// ---------------------------------------------------------------------------
__global__ __launch_bounds__(256) void attn(const unsigned short* __restrict__ QmHp,
                                            const unsigned short* __restrict__ QmLp,
                                            const unsigned short* __restrict__ Ccp,
                                            const unsigned short* __restrict__ KHp,
                                            const unsigned short* __restrict__ VTp,
                                            unsigned short* __restrict__ OB) {
    __shared__ unsigned short KsH[2][64 * 64], Vs[2][64 * 64];
    __shared__ unsigned short Ph[4][32 * 72];
    const int t = threadIdx.x, wv = t >> 6, lane = t & 63;
    const int fm = lane & 15, fq = lane >> 4;
    const int bh = blockIdx.y, q0 = blockIdx.x * 128;

    const unsigned short* qmh = QmHp + (size_t)bh * S_ * 64;
    const unsigned short* qml = QmLp + (size_t)bh * S_ * 64;
    const unsigned short* qcc = Ccp  + (size_t)bh * S_ * 64;
    const unsigned short* kh  = KHp  + (size_t)bh * S_ * 64;
    const unsigned short* vt  = VTp  + (size_t)bh * 64 * S_;

    const int srow = t >> 3;
    const int skb0 = t & 7;

    // prologue: stage K/V tile jt=0 into buf 0
#pragma unroll
    for (int i = 0; i < 2; ++i) {
        const int row = srow + 32 * i;
        const int kb = skb0 ^ (row & 7);
        const int dst = (wv * 64 + 256 * i) * 8;
        gload_lds16(kh + (size_t)row * 64 + kb * 8, &KsH[0][dst]);
        gload_lds16(vt + (size_t)row * S_ + kb * 8, &Vs[0][dst]);
    }

    // Assemble Q fragments: q = (Qm + C) * log2e, split hi/lo
    short8v qfh[2][2], qfl[2][2];
#pragma unroll
    for (int qt = 0; qt < 2; ++qt)
#pragma unroll
        for (int t2 = 0; t2 < 2; ++t2) {
            const size_t off = (size_t)(q0 + wv * 32 + qt * 16 + fm) * 64 + t2 * 32 + fq * 8;
            const ushort8v mh = *(const ushort8v*)&qmh[off];
            const ushort8v ml = *(const ushort8v*)&qml[off];
            const ushort8v cc = *(const ushort8v*)&qcc[off];
#pragma unroll
            for (int i = 0; i < 8; ++i) {
                const float v = (bf2f(mh[i]) + bf2f(ml[i]) + bf2f(cc[i])) * LOG2E;
                const unsigned short hh = f2bf(v);
                qfh[qt][t2][i] = (short)hh;
                qfl[qt][t2][i] = (short)f2bf(v - bf2f(hh));
            }
        }

    float4v accO[2][4];
#pragma unroll
    for (int qt = 0; qt < 2; ++qt)
#pragma unroll
        for (int dt = 0; dt < 4; ++dt) accO[qt][dt] = (float4v){0.f, 0.f, 0.f, 0.f};
    float lpart[2][4] = {};

    for (int jt = 0; jt < 32; ++jt) {
        __syncthreads();

        if (jt + 1 < 32) {
            const int j0n = (jt + 1) * 64;
            const int nbuf = (jt + 1) & 1;
#pragma unroll
            for (int i = 0; i < 2; ++i) {
                const int row = srow + 32 * i;
                const int kb = skb0 ^ (row & 7);
                const int dst = (wv * 64 + 256 * i) * 8;
                gload_lds16(kh + (size_t)(j0n + row) * 64 + kb * 8, &KsH[nbuf][dst]);
                gload_lds16(vt + (size_t)row * S_ + j0n + kb * 8, &Vs[nbuf][dst]);
            }
        }
        const int buf = jt & 1;

        // S = Q K^T (qh.k + ql.k)
        float4v accS[2][4];
#pragma unroll
        for (int qt = 0; qt < 2; ++qt)
#pragma unroll
            for (int st = 0; st < 4; ++st) accS[qt][st] = (float4v){0.f, 0.f, 0.f, 0.f};
#pragma unroll
        for (int t2 = 0; t2 < 2; ++t2)
#pragma unroll
            for (int st = 0; st < 4; ++st) {
                const int row = st * 16 + fm;
                const short8v kf = *(const short8v*)&KsH[buf][row * 64 + 8 * ((4 * t2 + fq) ^ (row & 7))];
#pragma unroll
                for (int qt = 0; qt < 2; ++qt) {
                    accS[qt][st] = __builtin_amdgcn_mfma_f32_16x16x32_bf16(qfh[qt][t2], kf, accS[qt][st], 0, 0, 0);
                    accS[qt][st] = __builtin_amdgcn_mfma_f32_16x16x32_bf16(qfl[qt][t2], kf, accS[qt][st], 0, 0, 0);
                }
            }

        // P = exp2(S); accumulate l; store P (trunc bf16) with rotation swizzle
#pragma unroll
        for (int qt = 0; qt < 2; ++qt)
#pragma unroll
            for (int st = 0; st < 4; ++st)
#pragma unroll
                for (int r = 0; r < 4; ++r) {
                    const float p = fast_exp2(accS[qt][st][r]);
                    lpart[qt][r] += p;
                    const int row = qt * 16 + 4 * fq + r;
                    Ph[wv][row * 72 + ((st * 16 + fm + 16 * fq) & 63)] = f2bf_trunc(p);
                }

        // O += P V (wave-private P buffer)
#pragma unroll
        for (int t2 = 0; t2 < 2; ++t2) {
            short8v pa[2];
#pragma unroll
            for (int qt = 0; qt < 2; ++qt) {
                const int row = qt * 16 + fm;
                pa[qt] = *(const short8v*)&Ph[wv][row * 72 + ((t2 * 32 + fq * 8 + 16 * (fm >> 2)) & 63)];
            }
#pragma unroll
            for (int dt = 0; dt < 4; ++dt) {
                const int vrow = dt * 16 + fm;
                const short8v vf = *(const short8v*)&Vs[buf][vrow * 64 + 8 * ((4 * t2 + fq) ^ (vrow & 7))];
#pragma unroll
                for (int qt = 0; qt < 2; ++qt)
                    accO[qt][dt] = __builtin_amdgcn_mfma_f32_16x16x32_bf16(pa[qt], vf, accO[qt][dt], 0, 0, 0);
            }
        }
    }

    // reduce l across the 16 m-lanes
#pragma unroll
    for (int qt = 0; qt < 2; ++qt)
#pragma unroll
        for (int r = 0; r < 4; ++r) {
            float v = lpart[qt][r];
            v += __shfl_xor(v, 1); v += __shfl_xor(v, 2);
            v += __shfl_xor(v, 4); v += __shfl_xor(v, 8);
            lpart[qt][r] = v;
        }

    // epilogue: o/l as bf16 into OB[b][s][h*64+d]
    const int b = bh >> 3, h = bh & 7;
#pragma unroll
    for (int qt = 0; qt < 2; ++qt)
#pragma unroll
        for (int r = 0; r < 4; ++r) {
            const float inv = 1.f / lpart[qt][r];
            const int q = q0 + wv * 32 + qt * 16 + 4 * fq + r;
#pragma unroll
            for (int dt = 0; dt < 4; ++dt)
                OB[((size_t)(b * 2048 + q)) * 512 + h * 64 + dt * 16 + fm] =
                    f2bf(accO[qt][dt][r] * inv);
        }
}

// ---------------------------------------------------------------------------
// GEMM2 (out projection), R8 version: 128x64 tile, dbuf + prefetch.
// ---------------------------------------------------------------------------
__global__ __launch_bounds__(256) void gemm_out(const unsigned short* __restrict__ OB,
                                                const unsigned short* __restrict__ Wob,
                                                float* __restrict__ out) {
    __shared__ unsigned short Asm[2][128 * 64];
    __shared__ unsigned short Bsm[2][64 * 64];
    const int t = threadIdx.x, wv = t >> 6, lane = t & 63;
    const int fm = lane & 15, fq = lane >> 4;
    const int m0 = blockIdx.y * 128, e0 = blockIdx.x * 64;
    const int wrow = (wv & 1) * 64, wcol = (wv >> 1) * 32;

    const int srow = t >> 3;
    const int skb0 = t & 7;

    float4v acc[4][2];
#pragma unroll
    for (int i = 0; i < 4; ++i)
#pragma unroll
        for (int j = 0; j < 2; ++j) acc[i][j] = (float4v){0.f, 0.f, 0.f, 0.f};

    // prologue: stage k0=0
#pragma unroll
    for (int i = 0; i < 4; ++i) {
        const int row = srow + 32 * i;
        const int kb = skb0 ^ (row & 7);
        gload_lds16(OB + (size_t)(m0 + row) * 512 + kb * 8,
                    &Asm[0][(wv * 64 + 256 * i) * 8]);
    }
#pragma unroll
    for (int i = 0; i < 2; ++i) {
        const int row = srow + 32 * i;
        const int kb = skb0 ^ (row & 7);
        gload_lds16(Wob + (size_t)(e0 + row) * 512 + kb * 8,
                    &Bsm[0][(wv * 64 + 256 * i) * 8]);
    }

    for (int kk = 0; kk < 8; ++kk) {
        __syncthreads();
        if (kk + 1 < 8) {
            const int k0n = (kk + 1) * 64, nbuf = (kk + 1) & 1;
#pragma unroll
            for (int i = 0; i < 4; ++i) {
                const int row = srow + 32 * i;
                const int kb = skb0 ^ (row & 7);
                gload_lds16(OB + (size_t)(m0 + row) * 512 + k0n + kb * 8,
                            &Asm[nbuf][(wv * 64 + 256 * i) * 8]);
            }
#pragma unroll
            for (int i = 0; i < 2; ++i) {
                const int row = srow + 32 * i;
                const int kb = skb0 ^ (row & 7);
                gload_lds16(Wob + (size_t)(e0 + row) * 512 + k0n + kb * 8,
                            &Bsm[nbuf][(wv * 64 + 256 * i) * 8]);
            }
        }
        const int buf = kk & 1;
#pragma unroll
        for (int ks = 0; ks < 2; ++ks) {
            short8v af[4], bf[2];
#pragma unroll
            for (int mt = 0; mt < 4; ++mt) {
                const int row = wrow + mt * 16 + fm;
                af[mt] = *(const short8v*)&Asm[buf][row * 64 + 8 * ((4 * ks + fq) ^ (row & 7))];
            }
#pragma unroll
            for (int nt = 0; nt < 2; ++nt) {
                const int row = wcol + nt * 16 + fm;
                bf[nt] = *(const short8v*)&Bsm[buf][row * 64 + 8 * ((4 * ks + fq) ^ (row & 7))];
            }
#pragma unroll
            for (int mt = 0; mt < 4; ++mt)
#pragma unroll
                for (int nt = 0; nt < 2; ++nt)
                    acc[mt][nt] = __builtin_amdgcn_mfma_f32_16x16x32_bf16(af[mt], bf[nt], acc[mt][nt], 0, 0, 0);
        }
    }
#pragma unroll
    for (int mt = 0; mt < 4; ++mt)
#pragma unroll
        for (int nt = 0; nt < 2; ++nt)
#pragma unroll
            for (int r = 0; r < 4; ++r) {
                const int m = m0 + wrow + mt * 16 + 4 * fq + r;
                const int e = e0 + wcol + nt * 16 + fm;
                out[(size_t)m * 512 + e] = acc[mt][nt][r];
            }
}

// ---------------------------------------------------------------------------
extern "C" void kernel_launch(void* const* d_in, const int* in_sizes, int n_in,
                              void* d_out, int out_size, void* d_ws, size_t ws_size,
                              hipStream_t stream) {
    const float* x     = (const float*)d_in[0];   // [B,S,D]
    const float* w_qkv = (const float*)d_in[1];   // [3D, D]
    const float* w_out = (const float*)d_in[2];   // [D, D]
    float* out = (float*)d_out;                   // [B,S,D]

    // workspace carve-up (bytes): total ~61.4 MB
    char* p = (char*)d_ws;
    unsigned short* Xp  = (unsigned short*)p;  p += (size_t)M_ * 1024 * 2;      // 16.8 MB
    unsigned short* Wh  = (unsigned short*)p;  p += (size_t)1536 * 512 * 2;     // 1.6 MB
    unsigned short* Wlq = (unsigned short*)p;  p += (size_t)512 * 512 * 2;      // 0.5 MB
    unsigned short* Wob = (unsigned short*)p;  p += (size_t)512 * 512 * 2;      // 0.5 MB
    unsigned short* QmH = (unsigned short*)p;  p += (size_t)32 * S_ * 64 * 2;   // 8.4 MB
    unsigned short* QmL = (unsigned short*)p;  p += (size_t)32 * S_ * 64 * 2;
    unsigned short* Cc  = (unsigned short*)p;  p += (size_t)32 * S_ * 64 * 2;
    unsigned short* KH  = (unsigned short*)p;  p += (size_t)32 * S_ * 64 * 2;
    unsigned short* VT  = (unsigned short*)p;  p += (size_t)32 * 64 * S_ * 2;
    unsigned short* OB  = Xp;  // Xp dead after gemm_qkv; reuse for attention output

    prepass<<<2560, 256, 0, stream>>>(x, w_qkv, w_out, Xp, Wh, Wlq, Wob);
    gemm_qkv<<<dim3(32, 64), 256, 0, stream>>>(Xp, Wh, Wlq, QmH, QmL, Cc, KH, VT);
    attn<<<dim3(16, 32), 256, 0, stream>>>(QmH, QmL, Cc, KH, VT, OB);
    gemm_out<<<dim3(8, 64), 256, 0, stream>>>(OB, Wob, out);
}